// Round 10
// baseline (89.476 us; speedup 1.0000x reference)
//
#include <hip/hip_runtime.h>

// RoIAlign-3D: x[2,256,16,64,64] f32, rois[128,5] -> out[128,256,16,7,7] f32
// R9b: bf16 4-plane-interleaved LDS (8B/texel chunk). LDS = 64 rows x 65
// chunks x 8B = 33.3KB -> 4 blocks/CU (32 waves). 3x3 window = 9 ds_read_b64
// per 4 outputs; pitch 65 chunks => +1 bank-slot per row (3-row window never
// self-collides). Manual bf16 pack (RNE bit-trick; __hip_bfloat162 is not
// trivially copyable for bit_cast). Padded per-image slot lists (dup-k,
// benign identical rewrites) -> uniform j trip, next-j meta prefetch.
// f32 weights. No T14 reg-prefetch (TLP at 4 blocks/CU covers it).

#define PITCHB 520    // 65 chunks * 8B per row

__global__ __launch_bounds__(256) void pooler_pre(const float* __restrict__ rois,
                                                  int* __restrict__ list,
                                                  int* __restrict__ jt,
                                                  uint4* __restrict__ meta) {
    __shared__ int simg[128];
    __shared__ int sorted[256];
    __shared__ int scnt[2];
    const int tid = threadIdx.x;
    if (tid < 128) simg[tid] = (int)rois[5 * tid];
    __syncthreads();
    if (tid == 0) {
        int c0 = 0, c1 = 0;
        for (int j = 0; j < 128; ++j) {
            if (simg[j] == 0) sorted[c0++] = j;
            else              sorted[128 + c1++] = j;
        }
        scnt[0] = c0; scnt[1] = c1;
        jt[0] = (c0 + 7) >> 3;
        jt[1] = (c1 + 7) >> 3;
    }
    __syncthreads();
    const int img = tid >> 7, idx = tid & 127;
    const int cnt = scnt[img];
    int k = 0;
    if (cnt > 0) k = (idx < cnt) ? sorted[(img << 7) + idx] : sorted[img << 7];
    list[tid] = k;   // pad slots duplicate the image's first ROI (identical rewrites)

    float x1 = rois[5*k+1]*0.25f, y1 = rois[5*k+2]*0.25f;
    float x2 = rois[5*k+3]*0.25f, y2 = rois[5*k+4]*0.25f;
    float bw = fmaxf(x2 - x1, 1.0f) * (1.0f / 14.0f);
    float bh = fmaxf(y2 - y1, 1.0f) * (1.0f / 14.0f);
    for (int i = 0; i < 7; ++i) {
        {   // ---- y: 2 samples -> 3-row weights (mask folded); clamp+shift
            float s0 = fmaf((float)(2*i) + 0.5f, bh, y1), s1 = s0 + bh;
            float m0 = (s0 >= -1.f && s0 <= 64.f) ? 1.f : 0.f;
            float m1 = (s1 >= -1.f && s1 <= 64.f) ? 1.f : 0.f;
            float c0 = fminf(fmaxf(s0, 0.f), 63.f), c1 = fminf(fmaxf(s1, 0.f), 63.f);
            int i0 = min((int)c0, 62), i1 = min((int)c1, 62);
            float l0 = c0 - (float)i0, l1 = c1 - (float)i1;
            float h0 = (1.f - l0) * m0, L0 = l0 * m0;
            float h1 = (1.f - l1) * m1, L1 = l1 * m1;
            bool d = (i1 != i0);
            float w0 = h0 + (d ? 0.f : h1);
            float w1 = L0 + (d ? h1 : L1);
            float w2 = d ? L1 : 0.f;            // ==0 when i0==62
            int b = i0;
            if (i0 > 61) { b = 61; w2 = w1; w1 = w0; w0 = 0.f; }
            uint4 e;
            e.x = __float_as_uint(w0); e.y = __float_as_uint(w1);
            e.z = __float_as_uint(w2); e.w = (unsigned)b;
            meta[tid * 14 + i] = e;
        }
        {   // ---- x: same, 1/4 sample-mean folded
            float s0 = fmaf((float)(2*i) + 0.5f, bw, x1), s1 = s0 + bw;
            float m0 = (s0 >= -1.f && s0 <= 64.f) ? 0.25f : 0.f;
            float m1 = (s1 >= -1.f && s1 <= 64.f) ? 0.25f : 0.f;
            float c0 = fminf(fmaxf(s0, 0.f), 63.f), c1 = fminf(fmaxf(s1, 0.f), 63.f);
            int i0 = min((int)c0, 62), i1 = min((int)c1, 62);
            float l0 = c0 - (float)i0, l1 = c1 - (float)i1;
            float h0 = (1.f - l0) * m0, L0 = l0 * m0;
            float h1 = (1.f - l1) * m1, L1 = l1 * m1;
            bool d = (i1 != i0);
            float w0 = h0 + (d ? 0.f : h1);
            float w1 = L0 + (d ? h1 : L1);
            float w2 = d ? L1 : 0.f;
            int b = i0;
            if (i0 > 61) { b = 61; w2 = w1; w1 = w0; w0 = 0.f; }
            uint4 e;
            e.x = __float_as_uint(w0); e.y = __float_as_uint(w1);
            e.z = __float_as_uint(w2); e.w = (unsigned)b;
            meta[tid * 14 + 7 + i] = e;
        }
    }
}

// bf16 pack (round-to-nearest-even) / unpack via bit ops.
__device__ __forceinline__ unsigned bfrne(float f) {
    unsigned u = __float_as_uint(f);
    return (u + 0x7FFFu + ((u >> 16) & 1u)) >> 16;
}
__device__ __forceinline__ unsigned pack2(float lo, float hi) {
    return bfrne(lo) | (bfrne(hi) << 16);
}
__device__ __forceinline__ float bflo(unsigned w) { return __uint_as_float(w << 16); }
__device__ __forceinline__ float bfhi(unsigned w) { return __uint_as_float(w & 0xFFFF0000u); }

__global__ __launch_bounds__(512, 8) void pooler_main(const float* __restrict__ x,
                                                      const int* __restrict__ list,
                                                      const int* __restrict__ jt,
                                                      const uint4* __restrict__ meta,
                                                      float* __restrict__ out) {
    __shared__ __align__(16) char lds[64 * PITCHB];   // 33,280 B -> 4 blocks/CU

    const int tid = threadIdx.x;
    const int bid = blockIdx.x;
    const int th  = bid & 1;
    const int c   = (bid >> 1) & 255;
    const int img = bid >> 9;
    const int sbase = img << 7;
    const int jtn = jt[img];

    const int lane = tid & 63, wave = tid >> 6;
    const int o  = lane;
    const int oc = o < 49 ? o : 48;
    const int ph = oc / 7, pw = oc - ph * 7;

    // (img,c) base + th*8 planes
    const float* gbase = x + (((size_t)((img << 8) + c)) << 16) + ((size_t)th << 15);

    for (int i = 0; i < 2; ++i) {
        __syncthreads();                   // previous round done reading LDS
        {   // stage 4 planes as bf16 4-plane chunks; linear conflict-free b64 writes
            const float* pb = gbase + (i << 14);
            #pragma unroll
            for (int m = 0; m < 8; ++m) {
                int n = tid + (m << 9);    // chunk index 0..4095 (texel y*64+x)
                float v0 = pb[n], v1 = pb[4096 + n], v2 = pb[8192 + n], v3 = pb[12288 + n];
                uint2 ch;
                ch.x = pack2(v0, v1);
                ch.y = pack2(v2, v3);
                *(uint2*)(lds + (n >> 6) * PITCHB + ((n & 63) << 3)) = ch;
            }
        }
        __syncthreads();
        if (jtn > 0) {
            const int tb = (th << 3) + (i << 2);
            int s0 = sbase + wave;
            int k0 = list[s0];
            uint4 ye0 = meta[s0 * 14 + ph];
            uint4 xe0 = meta[s0 * 14 + 7 + pw];
            for (int j = 0; j < jtn; ++j) {
                int sn = sbase + wave + (min(j + 1, jtn - 1) << 3);
                int k1 = list[sn];                      // prefetch next slot's meta
                uint4 ye1 = meta[sn * 14 + ph];
                uint4 xe1 = meta[sn * 14 + 7 + pw];

                float yw0 = __uint_as_float(ye0.x);
                float yw1 = __uint_as_float(ye0.y);
                float yw2 = __uint_as_float(ye0.z);
                float xw0 = __uint_as_float(xe0.x);
                float xw1 = __uint_as_float(xe0.y);
                float xw2 = __uint_as_float(xe0.z);
                int yb = (int)ye0.w, xb = (int)xe0.w;

                // 9 combined weights (rank-1), then 9 b64 chunk reads
                const char* p0 = lds + yb * PITCHB + (xb << 3);
                float w00 = yw0*xw0, w01 = yw0*xw1, w02 = yw0*xw2;
                float w10 = yw1*xw0, w11 = yw1*xw1, w12 = yw1*xw2;
                float w20 = yw2*xw0, w21 = yw2*xw1, w22 = yw2*xw2;

                uint2 q00 = *(const uint2*)(p0);
                uint2 q01 = *(const uint2*)(p0 + 8);
                uint2 q02 = *(const uint2*)(p0 + 16);
                uint2 q10 = *(const uint2*)(p0 + PITCHB);
                uint2 q11 = *(const uint2*)(p0 + PITCHB + 8);
                uint2 q12 = *(const uint2*)(p0 + PITCHB + 16);
                uint2 q20 = *(const uint2*)(p0 + 2 * PITCHB);
                uint2 q21 = *(const uint2*)(p0 + 2 * PITCHB + 8);
                uint2 q22 = *(const uint2*)(p0 + 2 * PITCHB + 16);

                float a0, a1, a2, a3;
                a0  = bflo(q00.x) * w00; a1  = bfhi(q00.x) * w00;
                a2  = bflo(q00.y) * w00; a3  = bfhi(q00.y) * w00;
                a0 += bflo(q01.x) * w01; a1 += bfhi(q01.x) * w01;
                a2 += bflo(q01.y) * w01; a3 += bfhi(q01.y) * w01;
                a0 += bflo(q02.x) * w02; a1 += bfhi(q02.x) * w02;
                a2 += bflo(q02.y) * w02; a3 += bfhi(q02.y) * w02;
                a0 += bflo(q10.x) * w10; a1 += bfhi(q10.x) * w10;
                a2 += bflo(q10.y) * w10; a3 += bfhi(q10.y) * w10;
                a0 += bflo(q11.x) * w11; a1 += bfhi(q11.x) * w11;
                a2 += bflo(q11.y) * w11; a3 += bfhi(q11.y) * w11;
                a0 += bflo(q12.x) * w12; a1 += bfhi(q12.x) * w12;
                a2 += bflo(q12.y) * w12; a3 += bfhi(q12.y) * w12;
                a0 += bflo(q20.x) * w20; a1 += bfhi(q20.x) * w20;
                a2 += bflo(q20.y) * w20; a3 += bfhi(q20.y) * w20;
                a0 += bflo(q21.x) * w21; a1 += bfhi(q21.x) * w21;
                a2 += bflo(q21.y) * w21; a3 += bfhi(q21.y) * w21;
                a0 += bflo(q22.x) * w22; a1 += bfhi(q22.x) * w22;
                a2 += bflo(q22.y) * w22; a3 += bfhi(q22.y) * w22;

                if (o < 49) {
                    float* po = out + (size_t)k0 * 200704 + (size_t)((c << 4) + tb) * 49 + o;
                    po[0]   = a0;
                    po[49]  = a1;
                    po[98]  = a2;
                    po[147] = a3;
                }
                k0 = k1; ye0 = ye1; xe0 = xe1;
            }
        }
    }
}

extern "C" void kernel_launch(void* const* d_in, const int* in_sizes, int n_in,
                              void* d_out, int out_size, void* d_ws, size_t ws_size,
                              hipStream_t stream) {
    const float* x    = (const float*)d_in[0];
    const float* rois = (const float*)d_in[1];
    float* out = (float*)d_out;
    int*   list = (int*)d_ws;
    int*   jtp  = (int*)((char*)d_ws + 1024);
    uint4* meta = (uint4*)((char*)d_ws + 2048);
    pooler_pre<<<1, 256, 0, stream>>>(rois, list, jtp, meta);
    pooler_main<<<1024, 512, 0, stream>>>(x, list, jtp, meta, out);
}

// Round 11
// 64.816 us; speedup vs baseline: 1.3805x; 1.3805x over previous
//
#include <hip/hip_runtime.h>

// RoIAlign-3D: x[2,256,16,64,64] f32, rois[128,5] -> out[128,256,16,7,7] f32
// R10: full-cacheline output streaming. Block = (img, c) with ALL 16 t-planes
// in LDS (bf16; per texel two 16B half-chunks in split A/B regions so the
// bank slot is (y+x)%8). One wave per ROI-slot j computes the whole (k,c)
// tile (16 t x 49 o) and flushes it via a per-wave LDS transpose buffer as
// 3136B = 49 full aligned cachelines (4 coalesced dwordx4 bursts). No partial
// lines -> no RMW write amplification (R9b's regression). Dynamic LDS 158KB.

#define LDS_B  66560      // B-half offset (planes 8..15)
#define LDS_OB 133120     // out-buffers: + wave*3136, 8 waves = 25088

__global__ __launch_bounds__(256) void pooler_pre(const float* __restrict__ rois,
                                                  int* __restrict__ list,
                                                  int* __restrict__ jt,
                                                  uint4* __restrict__ meta) {
    __shared__ int simg[128];
    __shared__ int sorted[256];
    __shared__ int scnt[2];
    const int tid = threadIdx.x;
    if (tid < 128) simg[tid] = (int)rois[5 * tid];
    __syncthreads();
    if (tid == 0) {
        int c0 = 0, c1 = 0;
        for (int j = 0; j < 128; ++j) {
            if (simg[j] == 0) sorted[c0++] = j;
            else              sorted[128 + c1++] = j;
        }
        scnt[0] = c0; scnt[1] = c1;
        jt[0] = (c0 + 7) >> 3;
        jt[1] = (c1 + 7) >> 3;
    }
    __syncthreads();
    const int img = tid >> 7, idx = tid & 127;
    const int cnt = scnt[img];
    int k = 0;
    if (cnt > 0) k = (idx < cnt) ? sorted[(img << 7) + idx] : sorted[img << 7];
    list[tid] = k;   // pad slots duplicate the image's first ROI (identical rewrites)

    float x1 = rois[5*k+1]*0.25f, y1 = rois[5*k+2]*0.25f;
    float x2 = rois[5*k+3]*0.25f, y2 = rois[5*k+4]*0.25f;
    float bw = fmaxf(x2 - x1, 1.0f) * (1.0f / 14.0f);
    float bh = fmaxf(y2 - y1, 1.0f) * (1.0f / 14.0f);
    for (int i = 0; i < 7; ++i) {
        {   // ---- y: 2 samples -> 3-row weights (mask folded); clamp+shift
            float s0 = fmaf((float)(2*i) + 0.5f, bh, y1), s1 = s0 + bh;
            float m0 = (s0 >= -1.f && s0 <= 64.f) ? 1.f : 0.f;
            float m1 = (s1 >= -1.f && s1 <= 64.f) ? 1.f : 0.f;
            float c0 = fminf(fmaxf(s0, 0.f), 63.f), c1 = fminf(fmaxf(s1, 0.f), 63.f);
            int i0 = min((int)c0, 62), i1 = min((int)c1, 62);
            float l0 = c0 - (float)i0, l1 = c1 - (float)i1;
            float h0 = (1.f - l0) * m0, L0 = l0 * m0;
            float h1 = (1.f - l1) * m1, L1 = l1 * m1;
            bool d = (i1 != i0);
            float w0 = h0 + (d ? 0.f : h1);
            float w1 = L0 + (d ? h1 : L1);
            float w2 = d ? L1 : 0.f;
            int b = i0;
            if (i0 > 61) { b = 61; w2 = w1; w1 = w0; w0 = 0.f; }
            uint4 e;
            e.x = __float_as_uint(w0); e.y = __float_as_uint(w1);
            e.z = __float_as_uint(w2); e.w = (unsigned)b;      // texel row
            meta[tid * 14 + i] = e;
        }
        {   // ---- x: same, 1/4 sample-mean folded
            float s0 = fmaf((float)(2*i) + 0.5f, bw, x1), s1 = s0 + bw;
            float m0 = (s0 >= -1.f && s0 <= 64.f) ? 0.25f : 0.f;
            float m1 = (s1 >= -1.f && s1 <= 64.f) ? 0.25f : 0.f;
            float c0 = fminf(fmaxf(s0, 0.f), 63.f), c1 = fminf(fmaxf(s1, 0.f), 63.f);
            int i0 = min((int)c0, 62), i1 = min((int)c1, 62);
            float l0 = c0 - (float)i0, l1 = c1 - (float)i1;
            float h0 = (1.f - l0) * m0, L0 = l0 * m0;
            float h1 = (1.f - l1) * m1, L1 = l1 * m1;
            bool d = (i1 != i0);
            float w0 = h0 + (d ? 0.f : h1);
            float w1 = L0 + (d ? h1 : L1);
            float w2 = d ? L1 : 0.f;
            int b = i0;
            if (i0 > 61) { b = 61; w2 = w1; w1 = w0; w0 = 0.f; }
            uint4 e;
            e.x = __float_as_uint(w0); e.y = __float_as_uint(w1);
            e.z = __float_as_uint(w2); e.w = (unsigned)b;      // texel col
            meta[tid * 14 + 7 + i] = e;
        }
    }
}

// bf16 pack (round-to-nearest-even) / unpack via bit ops.
__device__ __forceinline__ unsigned bfrne(float f) {
    unsigned u = __float_as_uint(f);
    return (u + 0x7FFFu + ((u >> 16) & 1u)) >> 16;
}
__device__ __forceinline__ unsigned pack2(float lo, float hi) {
    return bfrne(lo) | (bfrne(hi) << 16);
}
__device__ __forceinline__ float bflo(unsigned w) { return __uint_as_float(w << 16); }
__device__ __forceinline__ float bfhi(unsigned w) { return __uint_as_float(w & 0xFFFF0000u); }

__global__ __launch_bounds__(512, 2) void pooler_main(const float* __restrict__ x,
                                                      const int* __restrict__ list,
                                                      const int* __restrict__ jt,
                                                      const uint4* __restrict__ meta,
                                                      float* __restrict__ out) {
    extern __shared__ __align__(16) char smem[];

    const int tid = threadIdx.x;
    const int bid = blockIdx.x;
    const int c   = bid & 255;
    const int img = bid >> 8;
    const int sbase = img << 7;
    const int jtn = jt[img];

    const int lane = tid & 63, wave = tid >> 6;
    const int o  = lane;
    const int oc = o < 49 ? o : 48;
    const int ph = oc / 7, pw = oc - ph * 7;

    // ---- stage all 16 planes as bf16 half-chunks (A: planes 0-7, B: 8-15)
    const float* gb = x + ((size_t)((img << 8) + c) << 16);
    #pragma unroll 2
    for (int m = 0; m < 8; ++m) {
        int n = tid + (m << 9);            // texel 0..4095
        float v0  = gb[n];
        float v1  = gb[(1  << 12) + n];
        float v2  = gb[(2  << 12) + n];
        float v3  = gb[(3  << 12) + n];
        float v4  = gb[(4  << 12) + n];
        float v5  = gb[(5  << 12) + n];
        float v6  = gb[(6  << 12) + n];
        float v7  = gb[(7  << 12) + n];
        float v8  = gb[(8  << 12) + n];
        float v9  = gb[(9  << 12) + n];
        float v10 = gb[(10 << 12) + n];
        float v11 = gb[(11 << 12) + n];
        float v12 = gb[(12 << 12) + n];
        float v13 = gb[(13 << 12) + n];
        float v14 = gb[(14 << 12) + n];
        float v15 = gb[(15 << 12) + n];
        uint4 qa, qb;
        qa.x = pack2(v0,  v1);  qa.y = pack2(v2,  v3);
        qa.z = pack2(v4,  v5);  qa.w = pack2(v6,  v7);
        qb.x = pack2(v8,  v9);  qb.y = pack2(v10, v11);
        qb.z = pack2(v12, v13); qb.w = pack2(v14, v15);
        int y = n >> 6, xx = n & 63;
        int off = ((y * 65 + xx) << 4);    // 16B chunk; bank slot (y+x)%8
        *(uint4*)(smem + off)         = qa;
        *(uint4*)(smem + LDS_B + off) = qb;
    }
    __syncthreads();

    if (jtn > 0) {
        float* ob = (float*)(smem + LDS_OB + wave * 3136);
        int s0 = sbase + wave;
        int k0 = list[s0];
        uint4 ye0 = meta[s0 * 14 + ph];
        uint4 xe0 = meta[s0 * 14 + 7 + pw];
        for (int j = 0; j < jtn; ++j) {
            int sn = sbase + wave + (min(j + 1, jtn - 1) << 3);
            int k1 = list[sn];                      // prefetch next slot's meta
            uint4 ye1 = meta[sn * 14 + ph];
            uint4 xe1 = meta[sn * 14 + 7 + pw];

            float yw0 = __uint_as_float(ye0.x);
            float yw1 = __uint_as_float(ye0.y);
            float yw2 = __uint_as_float(ye0.z);
            float xw0 = __uint_as_float(xe0.x);
            float xw1 = __uint_as_float(xe0.y);
            float xw2 = __uint_as_float(xe0.z);
            int yb = (int)ye0.w, xb = (int)xe0.w;

            float a0=0.f,a1=0.f,a2=0.f,a3=0.f,a4=0.f,a5=0.f,a6=0.f,a7=0.f;
            float a8=0.f,a9=0.f,a10=0.f,a11=0.f,a12=0.f,a13=0.f,a14=0.f,a15=0.f;
            const char* pA = smem + ((yb * 65 + xb) << 4);
            #pragma unroll
            for (int r = 0; r < 3; ++r) {
                float wr = (r == 0) ? yw0 : ((r == 1) ? yw1 : yw2);
                const char* rowA = pA + r * (65 * 16);
                #pragma unroll
                for (int cc = 0; cc < 3; ++cc) {
                    float w = wr * ((cc == 0) ? xw0 : ((cc == 1) ? xw1 : xw2));
                    uint4 qa = *(const uint4*)(rowA + (cc << 4));
                    uint4 qb = *(const uint4*)(rowA + LDS_B + (cc << 4));
                    a0  += bflo(qa.x) * w;  a1  += bfhi(qa.x) * w;
                    a2  += bflo(qa.y) * w;  a3  += bfhi(qa.y) * w;
                    a4  += bflo(qa.z) * w;  a5  += bfhi(qa.z) * w;
                    a6  += bflo(qa.w) * w;  a7  += bfhi(qa.w) * w;
                    a8  += bflo(qb.x) * w;  a9  += bfhi(qb.x) * w;
                    a10 += bflo(qb.y) * w;  a11 += bfhi(qb.y) * w;
                    a12 += bflo(qb.z) * w;  a13 += bfhi(qb.z) * w;
                    a14 += bflo(qb.w) * w;  a15 += bfhi(qb.w) * w;
                }
            }
            // ---- transpose via wave-private LDS tile, then aligned flush
            if (o < 49) {
                ob[ 0*49 + o] = a0;   ob[ 1*49 + o] = a1;
                ob[ 2*49 + o] = a2;   ob[ 3*49 + o] = a3;
                ob[ 4*49 + o] = a4;   ob[ 5*49 + o] = a5;
                ob[ 6*49 + o] = a6;   ob[ 7*49 + o] = a7;
                ob[ 8*49 + o] = a8;   ob[ 9*49 + o] = a9;
                ob[10*49 + o] = a10;  ob[11*49 + o] = a11;
                ob[12*49 + o] = a12;  ob[13*49 + o] = a13;
                ob[14*49 + o] = a14;  ob[15*49 + o] = a15;
            }
            asm volatile("s_waitcnt lgkmcnt(0)" ::: "memory");  // wave-local ds drain
            __builtin_amdgcn_sched_barrier(0);
            float* gdst = out + (size_t)k0 * 200704 + (size_t)c * 784;
            #pragma unroll
            for (int rr = 0; rr < 4; ++rr) {
                int i4 = lane + (rr << 6);
                if (i4 < 196) {                     // 196 dwordx4 = 3136B = 49 lines
                    float4 v = *(const float4*)(ob + (i4 << 2));
                    *(float4*)(gdst + (i4 << 2)) = v;
                }
            }
            k0 = k1; ye0 = ye1; xe0 = xe1;
        }
    }
}

extern "C" void kernel_launch(void* const* d_in, const int* in_sizes, int n_in,
                              void* d_out, int out_size, void* d_ws, size_t ws_size,
                              hipStream_t stream) {
    const float* x    = (const float*)d_in[0];
    const float* rois = (const float*)d_in[1];
    float* out = (float*)d_out;
    int*   list = (int*)d_ws;
    int*   jtp  = (int*)((char*)d_ws + 1024);
    uint4* meta = (uint4*)((char*)d_ws + 2048);
    static const int LDS_BYTES = 133120 + 8 * 3136;   // 158,208
    hipFuncSetAttribute((const void*)pooler_main,
                        hipFuncAttributeMaxDynamicSharedMemorySize, LDS_BYTES);
    pooler_pre<<<1, 256, 0, stream>>>(rois, list, jtp, meta);
    pooler_main<<<512, 512, LDS_BYTES, stream>>>(x, list, jtp, meta, out);
}

// Round 12
// 59.031 us; speedup vs baseline: 1.5158x; 1.0980x over previous
//
#include <hip/hip_runtime.h>

// RoIAlign-3D: x[2,256,16,64,64] f32, rois[128,5] -> out[128,256,16,7,7] f32
// R11: block = (img, c, t-half). Stage 8 planes once as bf16 16B chunks
// ([64][65] chunk layout, 66.5KB -> 2 blocks/CU, stage/compute overlap via
// co-residency). Wave = one ROI-slot chain: per j, 9 ds_read_b128 -> 8
// outputs/lane (1.125 reads/out), ~160 VALU, 8 dword stores into a 1568B
// wave burst (L2 merges partials at 2-block residency; halves share 1/49
// lines). Uniform jtn (dup-k pad, benign identical rewrites) + next-j meta
// prefetch. f32 weights, bf16 texels (bit-op pack/unpack).

#define PITCHC 65
#define ROWB   (PITCHC * 16)   // 1040 B per texel row

__global__ __launch_bounds__(256) void pooler_pre(const float* __restrict__ rois,
                                                  int* __restrict__ list,
                                                  int* __restrict__ jt,
                                                  uint4* __restrict__ meta) {
    __shared__ int simg[128];
    __shared__ int sorted[256];
    __shared__ int scnt[2];
    const int tid = threadIdx.x;
    if (tid < 128) simg[tid] = (int)rois[5 * tid];
    __syncthreads();
    if (tid == 0) {
        int c0 = 0, c1 = 0;
        for (int j = 0; j < 128; ++j) {
            if (simg[j] == 0) sorted[c0++] = j;
            else              sorted[128 + c1++] = j;
        }
        scnt[0] = c0; scnt[1] = c1;
        jt[0] = (c0 + 7) >> 3;
        jt[1] = (c1 + 7) >> 3;
    }
    __syncthreads();
    const int img = tid >> 7, idx = tid & 127;
    const int cnt = scnt[img];
    int k = 0;
    if (cnt > 0) k = (idx < cnt) ? sorted[(img << 7) + idx] : sorted[img << 7];
    list[tid] = k;   // pad slots duplicate the image's first ROI (identical rewrites)

    float x1 = rois[5*k+1]*0.25f, y1 = rois[5*k+2]*0.25f;
    float x2 = rois[5*k+3]*0.25f, y2 = rois[5*k+4]*0.25f;
    float bw = fmaxf(x2 - x1, 1.0f) * (1.0f / 14.0f);
    float bh = fmaxf(y2 - y1, 1.0f) * (1.0f / 14.0f);
    for (int i = 0; i < 7; ++i) {
        {   // ---- y: 2 samples -> 3-row weights (mask folded); clamp+shift
            float s0 = fmaf((float)(2*i) + 0.5f, bh, y1), s1 = s0 + bh;
            float m0 = (s0 >= -1.f && s0 <= 64.f) ? 1.f : 0.f;
            float m1 = (s1 >= -1.f && s1 <= 64.f) ? 1.f : 0.f;
            float c0 = fminf(fmaxf(s0, 0.f), 63.f), c1 = fminf(fmaxf(s1, 0.f), 63.f);
            int i0 = min((int)c0, 62), i1 = min((int)c1, 62);
            float l0 = c0 - (float)i0, l1 = c1 - (float)i1;
            float h0 = (1.f - l0) * m0, L0 = l0 * m0;
            float h1 = (1.f - l1) * m1, L1 = l1 * m1;
            bool d = (i1 != i0);
            float w0 = h0 + (d ? 0.f : h1);
            float w1 = L0 + (d ? h1 : L1);
            float w2 = d ? L1 : 0.f;
            int b = i0;
            if (i0 > 61) { b = 61; w2 = w1; w1 = w0; w0 = 0.f; }
            uint4 e;
            e.x = __float_as_uint(w0); e.y = __float_as_uint(w1);
            e.z = __float_as_uint(w2); e.w = (unsigned)b;      // texel row
            meta[tid * 14 + i] = e;
        }
        {   // ---- x: same, 1/4 sample-mean folded
            float s0 = fmaf((float)(2*i) + 0.5f, bw, x1), s1 = s0 + bw;
            float m0 = (s0 >= -1.f && s0 <= 64.f) ? 0.25f : 0.f;
            float m1 = (s1 >= -1.f && s1 <= 64.f) ? 0.25f : 0.f;
            float c0 = fminf(fmaxf(s0, 0.f), 63.f), c1 = fminf(fmaxf(s1, 0.f), 63.f);
            int i0 = min((int)c0, 62), i1 = min((int)c1, 62);
            float l0 = c0 - (float)i0, l1 = c1 - (float)i1;
            float h0 = (1.f - l0) * m0, L0 = l0 * m0;
            float h1 = (1.f - l1) * m1, L1 = l1 * m1;
            bool d = (i1 != i0);
            float w0 = h0 + (d ? 0.f : h1);
            float w1 = L0 + (d ? h1 : L1);
            float w2 = d ? L1 : 0.f;
            int b = i0;
            if (i0 > 61) { b = 61; w2 = w1; w1 = w0; w0 = 0.f; }
            uint4 e;
            e.x = __float_as_uint(w0); e.y = __float_as_uint(w1);
            e.z = __float_as_uint(w2); e.w = (unsigned)b;      // texel col
            meta[tid * 14 + 7 + i] = e;
        }
    }
}

// bf16 pack (round-to-nearest-even) / unpack via bit ops.
__device__ __forceinline__ unsigned bfrne(float f) {
    unsigned u = __float_as_uint(f);
    return (u + 0x7FFFu + ((u >> 16) & 1u)) >> 16;
}
__device__ __forceinline__ unsigned pack2(float lo, float hi) {
    return bfrne(lo) | (bfrne(hi) << 16);
}
__device__ __forceinline__ float bflo(unsigned w) { return __uint_as_float(w << 16); }
__device__ __forceinline__ float bfhi(unsigned w) { return __uint_as_float(w & 0xFFFF0000u); }

__global__ __launch_bounds__(512, 4) void pooler_main(const float* __restrict__ x,
                                                      const int* __restrict__ list,
                                                      const int* __restrict__ jt,
                                                      const uint4* __restrict__ meta,
                                                      float* __restrict__ out) {
    __shared__ __align__(16) char lds[64 * ROWB];   // 66,560 B -> 2 blocks/CU

    const int tid = threadIdx.x;
    const int bid = blockIdx.x;
    const int h   = bid & 1;                // t-half
    const int c   = (bid >> 1) & 255;
    const int img = bid >> 9;
    const int sbase = img << 7;
    const int jtn = jt[img];

    const int lane = tid & 63, wave = tid >> 6;
    const int o  = lane;
    const int oc = o < 49 ? o : 48;
    const int ph = oc / 7, pw = oc - ph * 7;

    // ---- stage this half's 8 planes as bf16 chunks (texel-major, pitch 65)
    const float* gb = x + ((size_t)((((img << 8) + c) << 4) + (h << 3)) << 12);
    #pragma unroll
    for (int g = 0; g < 2; ++g) {
        int q = tid + (g << 9);             // quad 0..1023 -> texels 4q..4q+3
        float4 v0 = *(const float4*)(gb + (0 << 12) + (q << 2));
        float4 v1 = *(const float4*)(gb + (1 << 12) + (q << 2));
        float4 v2 = *(const float4*)(gb + (2 << 12) + (q << 2));
        float4 v3 = *(const float4*)(gb + (3 << 12) + (q << 2));
        float4 v4 = *(const float4*)(gb + (4 << 12) + (q << 2));
        float4 v5 = *(const float4*)(gb + (5 << 12) + (q << 2));
        float4 v6 = *(const float4*)(gb + (6 << 12) + (q << 2));
        float4 v7 = *(const float4*)(gb + (7 << 12) + (q << 2));
        float a0[4] = {v0.x, v0.y, v0.z, v0.w};
        float a1[4] = {v1.x, v1.y, v1.z, v1.w};
        float a2[4] = {v2.x, v2.y, v2.z, v2.w};
        float a3[4] = {v3.x, v3.y, v3.z, v3.w};
        float a4[4] = {v4.x, v4.y, v4.z, v4.w};
        float a5[4] = {v5.x, v5.y, v5.z, v5.w};
        float a6[4] = {v6.x, v6.y, v6.z, v6.w};
        float a7[4] = {v7.x, v7.y, v7.z, v7.w};
        int y = q >> 4, xb4 = (q & 15) << 2;
        char* d = lds + y * ROWB + (xb4 << 4);
        #pragma unroll
        for (int e = 0; e < 4; ++e) {
            uint4 ch;
            ch.x = pack2(a0[e], a1[e]);
            ch.y = pack2(a2[e], a3[e]);
            ch.z = pack2(a4[e], a5[e]);
            ch.w = pack2(a6[e], a7[e]);
            *(uint4*)(d + (e << 4)) = ch;
        }
    }
    __syncthreads();

    if (jtn > 0) {
        int s0 = sbase + wave;
        int k0 = list[s0];
        uint4 ye0 = meta[s0 * 14 + ph];
        uint4 xe0 = meta[s0 * 14 + 7 + pw];
        for (int j = 0; j < jtn; ++j) {
            int sn = sbase + wave + (min(j + 1, jtn - 1) << 3);
            int k1 = list[sn];                      // prefetch next slot's meta
            uint4 ye1 = meta[sn * 14 + ph];
            uint4 xe1 = meta[sn * 14 + 7 + pw];

            float yw0 = __uint_as_float(ye0.x);
            float yw1 = __uint_as_float(ye0.y);
            float yw2 = __uint_as_float(ye0.z);
            float xw0 = __uint_as_float(xe0.x);
            float xw1 = __uint_as_float(xe0.y);
            float xw2 = __uint_as_float(xe0.z);
            int yb = (int)ye0.w, xb = (int)xe0.w;

            const char* p0 = lds + yb * ROWB + (xb << 4);
            float w00 = yw0*xw0, w01 = yw0*xw1, w02 = yw0*xw2;
            float w10 = yw1*xw0, w11 = yw1*xw1, w12 = yw1*xw2;
            float w20 = yw2*xw0, w21 = yw2*xw1, w22 = yw2*xw2;

            uint4 q00 = *(const uint4*)(p0);
            uint4 q01 = *(const uint4*)(p0 + 16);
            uint4 q02 = *(const uint4*)(p0 + 32);
            uint4 q10 = *(const uint4*)(p0 + ROWB);
            uint4 q11 = *(const uint4*)(p0 + ROWB + 16);
            uint4 q12 = *(const uint4*)(p0 + ROWB + 32);
            uint4 q20 = *(const uint4*)(p0 + 2 * ROWB);
            uint4 q21 = *(const uint4*)(p0 + 2 * ROWB + 16);
            uint4 q22 = *(const uint4*)(p0 + 2 * ROWB + 32);

            float a0, a1, a2, a3, a4, a5, a6, a7;
            a0  = bflo(q00.x) * w00; a1  = bfhi(q00.x) * w00;
            a2  = bflo(q00.y) * w00; a3  = bfhi(q00.y) * w00;
            a4  = bflo(q00.z) * w00; a5  = bfhi(q00.z) * w00;
            a6  = bflo(q00.w) * w00; a7  = bfhi(q00.w) * w00;
            a0 += bflo(q01.x) * w01; a1 += bfhi(q01.x) * w01;
            a2 += bflo(q01.y) * w01; a3 += bfhi(q01.y) * w01;
            a4 += bflo(q01.z) * w01; a5 += bfhi(q01.z) * w01;
            a6 += bflo(q01.w) * w01; a7 += bfhi(q01.w) * w01;
            a0 += bflo(q02.x) * w02; a1 += bfhi(q02.x) * w02;
            a2 += bflo(q02.y) * w02; a3 += bfhi(q02.y) * w02;
            a4 += bflo(q02.z) * w02; a5 += bfhi(q02.z) * w02;
            a6 += bflo(q02.w) * w02; a7 += bfhi(q02.w) * w02;
            a0 += bflo(q10.x) * w10; a1 += bfhi(q10.x) * w10;
            a2 += bflo(q10.y) * w10; a3 += bfhi(q10.y) * w10;
            a4 += bflo(q10.z) * w10; a5 += bfhi(q10.z) * w10;
            a6 += bflo(q10.w) * w10; a7 += bfhi(q10.w) * w10;
            a0 += bflo(q11.x) * w11; a1 += bfhi(q11.x) * w11;
            a2 += bflo(q11.y) * w11; a3 += bfhi(q11.y) * w11;
            a4 += bflo(q11.z) * w11; a5 += bfhi(q11.z) * w11;
            a6 += bflo(q11.w) * w11; a7 += bfhi(q11.w) * w11;
            a0 += bflo(q12.x) * w12; a1 += bfhi(q12.x) * w12;
            a2 += bflo(q12.y) * w12; a3 += bfhi(q12.y) * w12;
            a4 += bflo(q12.z) * w12; a5 += bfhi(q12.z) * w12;
            a6 += bflo(q12.w) * w12; a7 += bfhi(q12.w) * w12;
            a0 += bflo(q20.x) * w20; a1 += bfhi(q20.x) * w20;
            a2 += bflo(q20.y) * w20; a3 += bfhi(q20.y) * w20;
            a4 += bflo(q20.z) * w20; a5 += bfhi(q20.z) * w20;
            a6 += bflo(q20.w) * w20; a7 += bfhi(q20.w) * w20;
            a0 += bflo(q21.x) * w21; a1 += bfhi(q21.x) * w21;
            a2 += bflo(q21.y) * w21; a3 += bfhi(q21.y) * w21;
            a4 += bflo(q21.z) * w21; a5 += bfhi(q21.z) * w21;
            a6 += bflo(q21.w) * w21; a7 += bfhi(q21.w) * w21;
            a0 += bflo(q22.x) * w22; a1 += bfhi(q22.x) * w22;
            a2 += bflo(q22.y) * w22; a3 += bfhi(q22.y) * w22;
            a4 += bflo(q22.z) * w22; a5 += bfhi(q22.z) * w22;
            a6 += bflo(q22.w) * w22; a7 += bfhi(q22.w) * w22;

            if (o < 49) {
                float* po = out + (size_t)k0 * 200704 + (size_t)c * 784 + (h << 3) * 49 + o;
                po[0]     = a0;
                po[49]    = a1;
                po[98]    = a2;
                po[147]   = a3;
                po[196]   = a4;
                po[245]   = a5;
                po[294]   = a6;
                po[343]   = a7;
            }
            k0 = k1; ye0 = ye1; xe0 = xe1;
        }
    }
}

extern "C" void kernel_launch(void* const* d_in, const int* in_sizes, int n_in,
                              void* d_out, int out_size, void* d_ws, size_t ws_size,
                              hipStream_t stream) {
    const float* x    = (const float*)d_in[0];
    const float* rois = (const float*)d_in[1];
    float* out = (float*)d_out;
    int*   list = (int*)d_ws;
    int*   jtp  = (int*)((char*)d_ws + 1024);
    uint4* meta = (uint4*)((char*)d_ws + 2048);
    pooler_pre<<<1, 256, 0, stream>>>(rois, list, jtp, meta);
    pooler_main<<<1024, 512, 0, stream>>>(x, list, jtp, meta, out);
}